// Round 2
// baseline (214.138 us; speedup 1.0000x reference)
//
#include <hip/hip_runtime.h>

#define HQ 32
#define HKV 8
#define DH 128
#define WIN 256
#define META 128
#define SCALE 0.08838834764831845f

typedef __attribute__((ext_vector_type(8))) __bf16 bf16x8;
typedef __attribute__((ext_vector_type(16))) float f32x16;
typedef unsigned short u16;
typedef unsigned int u32;

__device__ __forceinline__ u16 f2bf(float f) {
  u32 u = __float_as_uint(f);
  u += 0x7FFFu + ((u >> 16) & 1u);
  return (u16)(u >> 16);
}

// ---------- prep: RoPE(K) -> bf16 Kr[hk][s][d] ----------
__global__ __launch_bounds__(256)
void prep_k(const float* __restrict__ Kg, u16* __restrict__ Kr, int S) {
  const int hk = blockIdx.x;
  const int s  = blockIdx.y * 128 + (threadIdx.x >> 1);
  const int h  = (threadIdx.x & 1) * 32;
  const float pos = (float)s;
  const float* src = Kg + ((size_t)s * HKV + hk) * DH;
  u16* dst = Kr + ((size_t)hk * S + s) * DH;
  #pragma unroll
  for (int c0 = h; c0 < h + 32; c0 += 8) {
    float x[8], y[8];
    *(float4*)&x[0] = *(const float4*)(src + c0);
    *(float4*)&x[4] = *(const float4*)(src + c0 + 4);
    *(float4*)&y[0] = *(const float4*)(src + c0 + 64);
    *(float4*)&y[4] = *(const float4*)(src + c0 + 68);
    u16 lo[8], hb[8];
    #pragma unroll
    for (int j = 0; j < 8; ++j) {
      float iv = __expf(-0.14391156831212787f * (float)(c0 + j)); // 10000^(-c/64)
      float sv, cv; __sincosf(pos * iv, &sv, &cv);
      lo[j] = f2bf(x[j] * cv - y[j] * sv);
      hb[j] = f2bf(y[j] * cv + x[j] * sv);
    }
    __builtin_memcpy(dst + c0, lo, 16);
    __builtin_memcpy(dst + c0 + 64, hb, 16);
  }
}

// ---------- prep: V -> bf16 Vt[hk][d][s], sigma-permuted within 64-blocks ----------
// sigma(r) = 2*(r&31) + (r>>5): lets main kernel write P pairs (c, c+32) as one b32.
__global__ __launch_bounds__(256)
void prep_v(const float* __restrict__ Vg, u16* __restrict__ Vt, int S) {
  __shared__ float T[64][132];
  const int hk = blockIdx.x;
  const int s0 = blockIdx.y * 64;
  {
    const int r = threadIdx.x >> 2;
    const int c = (threadIdx.x & 3) * 32;
    const float* src = Vg + ((size_t)(s0 + r) * HKV + hk) * DH + c;
    #pragma unroll
    for (int j = 0; j < 32; j += 4)
      *(float4*)&T[r][c + j] = *(const float4*)(src + j);
  }
  __syncthreads();
  {
    const int d = threadIdx.x >> 1;
    const int h = (threadIdx.x & 1) * 32;
    u16 buf[32];
    #pragma unroll
    for (int i = 0; i < 32; ++i) {
      const int p  = h + i;                     // sigma-space position
      const int rr = (p >> 1) + ((p & 1) << 5); // source kv offset
      buf[i] = f2bf(T[rr][d]);
    }
    u16* dst = Vt + ((size_t)hk * DH + d) * S + s0 + h;
    #pragma unroll
    for (int j = 0; j < 4; ++j)
      *(int4*)(dst + j * 8) = *(int4*)&buf[j * 8];
  }
}

// ---------- main: flash attention, 64-wide kv tiles ----------
__global__ __launch_bounds__(256, 2)
void attn_main(const float* __restrict__ Qg, const u16* __restrict__ Kr,
               const u16* __restrict__ Vt, float* __restrict__ Og, int S) {
  const int h    = blockIdx.x;
  const int q0   = blockIdx.y * 128;
  const int hk   = h >> 2;
  const int tid  = threadIdx.x;
  const int lane = tid & 63;
  const int wave = tid >> 6;
  const int ln31 = lane & 31;
  const int hi   = lane >> 5;
  const int kh   = hi * 8;

  // Overlaid LDS: phase A uses [0,34816) as Qs; loop uses Ks(17408)+Vs(18432)+Ps(18432)
  __shared__ __align__(16) char smem[54272];
  u16 (*Qs)[136] = (u16(*)[136])smem;              // 128 x 136
  u16 (*Ks)[136] = (u16(*)[136])smem;              // 64 x 136
  u16 (*Vs)[72]  = (u16(*)[72])(smem + 17408);     // 128 x 72 (kv sigma-order)
  u16 (*Ps)[72]  = (u16(*)[72])(smem + 35840);     // (4*32) x 72 (kv sigma-order)

  // ---- Phase A: stage Q with RoPE * scale, then pull A-frags to registers ----
  {
    const int r  = tid >> 1;
    const int c0 = (tid & 1) * 32;
    const float pos = (float)(q0 + r);
    const float* qrow = Qg + ((size_t)(q0 + r) * HQ + h) * DH;
    #pragma unroll
    for (int c = c0; c < c0 + 32; c += 8) {
      float x[8], y[8];
      *(float4*)&x[0] = *(const float4*)(qrow + c);
      *(float4*)&x[4] = *(const float4*)(qrow + c + 4);
      *(float4*)&y[0] = *(const float4*)(qrow + c + 64);
      *(float4*)&y[4] = *(const float4*)(qrow + c + 68);
      u16 lo[8], hb[8];
      #pragma unroll
      for (int j = 0; j < 8; ++j) {
        float iv = __expf(-0.14391156831212787f * (float)(c + j));
        float sv, cv; __sincosf(pos * iv, &sv, &cv);
        lo[j] = f2bf((x[j] * cv - y[j] * sv) * SCALE);
        hb[j] = f2bf((y[j] * cv + x[j] * sv) * SCALE);
      }
      __builtin_memcpy(&Qs[r][c], lo, 16);
      __builtin_memcpy(&Qs[r][c + 64], hb, 16);
    }
  }
  __syncthreads();
  bf16x8 qa[8];
  {
    const u16* qb = &Qs[wave * 32 + ln31][kh];
    #pragma unroll
    for (int kk = 0; kk < 8; ++kk) qa[kk] = *(const bf16x8*)(qb + kk * 16);
  }
  __syncthreads();   // Qs dead; region becomes Ks/Vs

  int wstart = q0 - WIN; if (wstart < META) wstart = META;
  int nwin = (q0 + 128 - wstart) >> 6; if (nwin < 0) nwin = 0;
  const int ntiles = 2 + nwin;   // 2 meta tiles (kv 0..127) + window tiles

  const int qw0 = q0 + wave * 32;
  f32x16 acc[4];
  #pragma unroll
  for (int d = 0; d < 4; ++d)
    #pragma unroll
    for (int r = 0; r < 16; ++r) acc[d][r] = 0.f;
  float m_i[16], l_i[16];
  #pragma unroll
  for (int r = 0; r < 16; ++r) { m_i[r] = -1e30f; l_i[r] = 0.f; }

  // staging: thread owns 64B of K (row tid>>2, chunk tid&3) and 64B of V (row tid>>1, half tid&1)
  const u16* Kbase = Kr + (size_t)hk * S * DH + tid * 32;
  const u16* Vbase = Vt + ((size_t)hk * DH + (tid >> 1)) * S + (tid & 1) * 32;

  int4 kp[4], vp[4];
  auto load_t = [&](int kv0) {
    const int4* ks = (const int4*)(Kbase + (size_t)kv0 * DH);
    kp[0] = ks[0]; kp[1] = ks[1]; kp[2] = ks[2]; kp[3] = ks[3];
    const int4* vs = (const int4*)(Vbase + kv0);
    vp[0] = vs[0]; vp[1] = vs[1]; vp[2] = vs[2]; vp[3] = vs[3];
  };
  auto store_t = [&]() {
    int4* kd = (int4*)&Ks[tid >> 2][(tid & 3) * 32];
    kd[0] = kp[0]; kd[1] = kp[1]; kd[2] = kp[2]; kd[3] = kp[3];
    int4* vd = (int4*)&Vs[tid >> 1][(tid & 1) * 32];
    vd[0] = vp[0]; vd[1] = vp[1]; vd[2] = vp[2]; vd[3] = vp[3];
  };

  load_t(0);
  store_t();
  __syncthreads();

  for (int t = 0; t < ntiles; ++t) {
    const int kv0 = (t < 2) ? t * 64 : wstart + (t - 2) * 64;
    const bool last = (t + 1 == ntiles);
    if (!last) {                       // prefetch next tile into registers
      const int kvn = (t == 0) ? 64 : wstart + (t - 1) * 64;
      load_t(kvn);
    }

    if (kv0 <= qw0 + 31) {             // wave-uniform activity test
      // ---- S = Q K^T over 64 kv cols (two 32x32 C-tiles) ----
      f32x16 s0, s1;
      #pragma unroll
      for (int r = 0; r < 16; ++r) { s0[r] = 0.f; s1[r] = 0.f; }
      const u16* kb0 = &Ks[ln31][kh];
      const u16* kb1 = &Ks[32 + ln31][kh];
      #pragma unroll
      for (int kk = 0; kk < 8; ++kk)
        s0 = __builtin_amdgcn_mfma_f32_32x32x16_bf16(qa[kk], *(const bf16x8*)(kb0 + kk * 16), s0, 0, 0, 0);
      #pragma unroll
      for (int kk = 0; kk < 8; ++kk)
        s1 = __builtin_amdgcn_mfma_f32_32x32x16_bf16(qa[kk], *(const bf16x8*)(kb1 + kk * 16), s1, 0, 0, 0);

      // ---- online softmax over 64 cols; fast path when tile fully valid ----
      const int col0 = kv0 + ln31;
      const int col1 = col0 + 32;
      const bool fullv = (kv0 + 63 <= qw0) &&
                         ((kv0 >= qw0 + 31 - WIN) || (kv0 + 63 < META));
      #pragma unroll
      for (int r = 0; r < 16; ++r) {
        const int row = (r & 3) + 8 * (r >> 2) + 4 * hi;
        float a0 = s0[r], a1 = s1[r];
        if (!fullv) {
          const int qrow = qw0 + row;
          const bool v0 = (col0 <= qrow) && (((qrow - col0) <= WIN) || (col0 < META));
          const bool v1 = (col1 <= qrow) && (((qrow - col1) <= WIN) || (col1 < META));
          a0 = v0 ? a0 : -1e30f;     // exp(-1e30 - m) flushes to 0
          a1 = v1 ? a1 : -1e30f;
        }
        float mx = fmaxf(a0, a1);
        mx = fmaxf(mx, __shfl_xor(mx, 1));
        mx = fmaxf(mx, __shfl_xor(mx, 2));
        mx = fmaxf(mx, __shfl_xor(mx, 4));
        mx = fmaxf(mx, __shfl_xor(mx, 8));
        mx = fmaxf(mx, __shfl_xor(mx, 16));
        const float mnew = fmaxf(m_i[r], mx);
        const float al = __expf(m_i[r] - mnew);
        const float p0 = __expf(a0 - mnew);
        const float p1 = __expf(a1 - mnew);
        float ps = p0 + p1;
        ps += __shfl_xor(ps, 1);
        ps += __shfl_xor(ps, 2);
        ps += __shfl_xor(ps, 4);
        ps += __shfl_xor(ps, 8);
        ps += __shfl_xor(ps, 16);
        l_i[r] = l_i[r] * al + ps;
        m_i[r] = mnew;
        acc[0][r] *= al; acc[1][r] *= al; acc[2][r] *= al; acc[3][r] *= al;
        // sigma layout: col c -> slot 2*(c&31)+(c>>5); pack (p0,p1) into one b32
        const u32 pk = ((u32)f2bf(p1) << 16) | (u32)f2bf(p0);
        *(u32*)&Ps[wave * 32 + row][ln31 * 2] = pk;
      }

      // ---- O += P V (Ps wave-private: in-order LDS, no barrier needed) ----
      bf16x8 pa[4];
      const u16* pb = &Ps[wave * 32 + ln31][kh];
      #pragma unroll
      for (int kk = 0; kk < 4; ++kk) pa[kk] = *(const bf16x8*)(pb + kk * 16);
      #pragma unroll
      for (int d = 0; d < 4; ++d) {
        const u16* vb = &Vs[d * 32 + ln31][kh];
        #pragma unroll
        for (int kk = 0; kk < 4; ++kk)
          acc[d] = __builtin_amdgcn_mfma_f32_32x32x16_bf16(pa[kk], *(const bf16x8*)(vb + kk * 16), acc[d], 0, 0, 0);
      }
    }

    if (!last) {
      __syncthreads();   // all waves done reading Ks/Vs
      store_t();         // write prefetched tile (vmcnt drains here)
      __syncthreads();
    }
  }

  // ---- epilogue ----
  #pragma unroll
  for (int r = 0; r < 16; ++r) {
    const int row = (r & 3) + 8 * (r >> 2) + 4 * hi;
    const float inv = 1.0f / l_i[r];
    float* orow = Og + ((size_t)(qw0 + row) * HQ + h) * DH + ln31;
    #pragma unroll
    for (int d = 0; d < 4; ++d) orow[d * 32] = acc[d][r] * inv;
  }
}

extern "C" void kernel_launch(void* const* d_in, const int* in_sizes, int n_in,
                              void* d_out, int out_size, void* d_ws, size_t ws_size,
                              hipStream_t stream) {
  const float* Qg = (const float*)d_in[0];
  const float* Kg = (const float*)d_in[1];
  const float* Vg = (const float*)d_in[2];
  float* Og = (float*)d_out;
  const int S = in_sizes[0] / (HQ * DH);   // 2176

  u16* Kr = (u16*)d_ws;                                  // 8*S*128 bf16 = 4.45 MB
  u16* Vt = (u16*)((char*)d_ws + (size_t)HKV * S * DH * 2); // 4.45 MB

  prep_k<<<dim3(HKV, S / 128), dim3(256), 0, stream>>>(Kg, Kr, S);
  prep_v<<<dim3(HKV, S / 64),  dim3(256), 0, stream>>>(Vg, Vt, S);
  attn_main<<<dim3(HQ, S / 128), dim3(256), 0, stream>>>(Qg, Kr, Vt, Og, S);
}

// Round 3
// 177.065 us; speedup vs baseline: 1.2094x; 1.2094x over previous
//
#include <hip/hip_runtime.h>

#define HQ 32
#define HKV 8
#define DH 128
#define WIN 256
#define META 128
#define QSCALE 0.1275174324f    // rsqrt(128) * log2(e)  (scores produced in log2 space)
#define NFREQ 0.20762050594046f // log2(10000)/64: invfreq(i) = exp2(-NFREQ*i)

typedef __attribute__((ext_vector_type(8))) __bf16 bf16x8;
typedef __attribute__((ext_vector_type(16))) float f32x16;
typedef __attribute__((ext_vector_type(4))) unsigned int u32x4;
typedef unsigned short u16;
typedef unsigned int u32;

__device__ __forceinline__ u16 f2bf(float f) {
  u32 u = __float_as_uint(f);
  u += 0x7FFFu + ((u >> 16) & 1u);
  return (u16)(u >> 16);
}
__device__ __forceinline__ u32 packbf(float a, float b) {  // a->lo16, b->hi16
  u32 ua = __float_as_uint(a); ua += 0x7FFFu + ((ua >> 16) & 1u);
  u32 ub = __float_as_uint(b); ub += 0x7FFFu + ((ub >> 16) & 1u);
  return (ua >> 16) | (ub & 0xFFFF0000u);
}

// ---------- prep: RoPE(K) -> Kr[hk][s][d] bf16 ; V -> Vt[hk][d][s] bf16 ----------
__global__ __launch_bounds__(256)
void prep_kv(const float* __restrict__ Kg, const float* __restrict__ Vg,
             u16* __restrict__ Kr, u16* __restrict__ Vt, int S) {
  __shared__ float T[64][132];
  const int hk = blockIdx.x;
  const int s0 = blockIdx.y * 64;
  const int tid = threadIdx.x;
  // K rope: 4 threads/row, 16 pairs each
  {
    const int r = tid >> 2, c0 = (tid & 3) * 16;
    const int s = s0 + r;
    const float pos = (float)s;
    const float* src = Kg + ((size_t)s * HKV + hk) * DH;
    u16* dst = Kr + ((size_t)hk * S + s) * DH;
    float x[16], y[16];
    #pragma unroll
    for (int j = 0; j < 16; j += 4) {
      *(float4*)&x[j] = *(const float4*)(src + c0 + j);
      *(float4*)&y[j] = *(const float4*)(src + c0 + 64 + j);
    }
    u16 lo[16], hb[16];
    #pragma unroll
    for (int j = 0; j < 16; ++j) {
      float iv = __builtin_amdgcn_exp2f(-NFREQ * (float)(c0 + j));
      float sv, cv; __sincosf(pos * iv, &sv, &cv);
      lo[j] = f2bf(x[j] * cv - y[j] * sv);
      hb[j] = f2bf(y[j] * cv + x[j] * sv);
    }
    *(int4*)(dst + c0)      = *(int4*)&lo[0];
    *(int4*)(dst + c0 + 8)  = *(int4*)&lo[8];
    *(int4*)(dst + c0 + 64) = *(int4*)&hb[0];
    *(int4*)(dst + c0 + 72) = *(int4*)&hb[8];
  }
  // V transpose: stage fp32, write d-major bf16
  {
    const int r = tid >> 2, c = (tid & 3) * 32;
    const float* src = Vg + ((size_t)(s0 + r) * HKV + hk) * DH + c;
    #pragma unroll
    for (int j = 0; j < 32; j += 4) *(float4*)&T[r][c + j] = *(const float4*)(src + j);
  }
  __syncthreads();
  {
    const int d = tid >> 1, hf = (tid & 1) * 32;
    u16 buf[32];
    #pragma unroll
    for (int i = 0; i < 32; ++i) buf[i] = f2bf(T[hf + i][d]);
    u16* dst = Vt + ((size_t)hk * DH + d) * S + s0 + hf;
    #pragma unroll
    for (int j = 0; j < 4; ++j) *(int4*)(dst + j * 8) = *(int4*)&buf[j * 8];
  }
}

// ---------- main: flash attention, S^T/O^T orientation (q lives in lanes) ----------
__global__ __launch_bounds__(256, 4)
void attn_main(const float* __restrict__ Qg, const u16* __restrict__ Kr,
               const u16* __restrict__ Vt, float* __restrict__ Og, int S) {
  const int h = blockIdx.x;
  const int q0 = blockIdx.y * 128;
  const int hk = h >> 2;
  const int tid = threadIdx.x;
  const int lane = tid & 63;
  const int wave = tid >> 6;
  const int ln31 = lane & 31;
  const int hi = lane >> 5;
  const int kh = hi * 8;

  // Overlay: prologue Qs[128][136] (34816 B); loop Ks[64][136] + Vs[128][72] (35840 B)
  __shared__ __align__(16) char smem[35840];
  u16 (*Qs)[136] = (u16(*)[136])smem;
  u16 (*Ks)[136] = (u16(*)[136])smem;
  u16 (*Vs)[72]  = (u16(*)[72])(smem + 17408);

  // ---- prologue: stage Q with RoPE * QSCALE (log2e folded) ----
  {
    const int r = tid >> 1, c0 = (tid & 1) * 32;
    const float pos = (float)(q0 + r);
    const float* qrow = Qg + ((size_t)(q0 + r) * HQ + h) * DH;
    #pragma unroll
    for (int c = c0; c < c0 + 32; c += 8) {
      float x[8], y[8];
      *(float4*)&x[0] = *(const float4*)(qrow + c);
      *(float4*)&x[4] = *(const float4*)(qrow + c + 4);
      *(float4*)&y[0] = *(const float4*)(qrow + c + 64);
      *(float4*)&y[4] = *(const float4*)(qrow + c + 68);
      u16 lo[8], hb[8];
      #pragma unroll
      for (int j = 0; j < 8; ++j) {
        float iv = __builtin_amdgcn_exp2f(-NFREQ * (float)(c + j));
        float sv, cv; __sincosf(pos * iv, &sv, &cv);
        lo[j] = f2bf((x[j] * cv - y[j] * sv) * QSCALE);
        hb[j] = f2bf((y[j] * cv + x[j] * sv) * QSCALE);
      }
      __builtin_memcpy(&Qs[r][c], lo, 16);
      __builtin_memcpy(&Qs[r][c + 64], hb, 16);
    }
  }
  __syncthreads();
  const int qw0 = q0 + wave * 32;
  const int q = qw0 + ln31;           // this lane's q row (S^T col)
  bf16x8 qa[8];                       // B-operand frags: Q[q][k = kh + 16*kk + j]
  {
    const u16* qb = &Qs[wave * 32 + ln31][kh];
    #pragma unroll
    for (int kk = 0; kk < 8; ++kk) qa[kk] = *(const bf16x8*)(qb + kk * 16);
  }
  // loop-top __syncthreads() orders Qs reads before Ks/Vs overwrite

  int wstart = q0 - WIN; if (wstart < META) wstart = META;
  int nwin = (q0 + 128 - wstart) >> 6; if (nwin < 0) nwin = 0;
  const int ntiles = 2 + nwin;        // meta tiles first (guarantees finite m after t=0)

  f32x16 acc[4];                      // O^T: acc[dt] rows d=dt*32+pattern, col q=lane
  #pragma unroll
  for (int d = 0; d < 4; ++d)
    #pragma unroll
    for (int r = 0; r < 16; ++r) acc[d][r] = 0.f;
  float m_i = -1e30f, l_i = 0.f;      // one scalar per lane(=q row)!

  const u16* Kb = Kr + (size_t)hk * S * DH;
  const u16* Vb = Vt + ((size_t)hk * DH + (tid >> 1)) * S + (tid & 1) * 32;
  const int kr = tid >> 2, kc = (tid & 3) * 32;

  for (int t = 0; t < ntiles; ++t) {
    const int kv0 = (t < 2) ? t * 64 : wstart + (t - 2) * 64;

    __syncthreads();  // previous tile's readers done (t=0: Qs frag reads done)
    {   // stage K tile: 64 rows x 128d, 64 B/thread
      const int4* ks = (const int4*)(Kb + (size_t)(kv0 + kr) * DH + kc);
      int4 a = ks[0], b = ks[1], c = ks[2], d = ks[3];
      int4* kd = (int4*)&Ks[kr][kc];
      kd[0] = a; kd[1] = b; kd[2] = c; kd[3] = d;
    }
    {   // stage V^T tile: 128 d-rows x 64 kv, 64 B/thread
      const int4* vs = (const int4*)(Vb + kv0);
      int4 a = vs[0], b = vs[1], c = vs[2], d = vs[3];
      int4* vd = (int4*)&Vs[tid >> 1][(tid & 1) * 32];
      vd[0] = a; vd[1] = b; vd[2] = c; vd[3] = d;
    }
    __syncthreads();

    // wave-active: causal reach AND not window-expired (meta tiles never expire)
    const bool active = (kv0 <= qw0 + 31) &&
                        ((kv0 < META) || (qw0 - kv0 - 63 <= WIN));
    if (!active) continue;

    // ---- S^T = K Q^T : two 32x32 C-tiles (kv rows in regs, q in lanes) ----
    f32x16 s0v, s1v;
    #pragma unroll
    for (int r = 0; r < 16; ++r) { s0v[r] = 0.f; s1v[r] = 0.f; }
    const u16* ka0 = &Ks[ln31][kh];
    const u16* ka1 = &Ks[32 + ln31][kh];
    #pragma unroll
    for (int kk = 0; kk < 8; ++kk)
      s0v = __builtin_amdgcn_mfma_f32_32x32x16_bf16(*(const bf16x8*)(ka0 + kk * 16), qa[kk], s0v, 0, 0, 0);
    #pragma unroll
    for (int kk = 0; kk < 8; ++kk)
      s1v = __builtin_amdgcn_mfma_f32_32x32x16_bf16(*(const bf16x8*)(ka1 + kk * 16), qa[kk], s1v, 0, 0, 0);

    // ---- mask (in-register, per kv value) ----
    const bool fullv = (kv0 + 63 <= qw0) &&
                       ((kv0 + 63 < META) || (qw0 + 31 - kv0 <= WIN));
    if (!fullv) {
      #pragma unroll
      for (int r = 0; r < 16; ++r) {
        const int kva = kv0 + (r & 3) + 8 * (r >> 2) + 4 * hi;
        const int kvb = kva + 32;
        if (!((kva <= q) && (((q - kva) <= WIN) || (kva < META)))) s0v[r] = -1e30f;
        if (!((kvb <= q) && (((q - kvb) <= WIN) || (kvb < META)))) s1v[r] = -1e30f;
      }
    }

    // ---- online softmax: register reduction + ONE cross-half shuffle each ----
    float mx = -1e30f;
    #pragma unroll
    for (int r = 0; r < 16; ++r) mx = fmaxf(mx, fmaxf(s0v[r], s1v[r]));
    mx = fmaxf(mx, __shfl_xor(mx, 32));
    const float mnew = fmaxf(m_i, mx);
    const float al = __builtin_amdgcn_exp2f(m_i - mnew);
    m_i = mnew;
    float ps = 0.f;
    #pragma unroll
    for (int r = 0; r < 16; ++r) {
      s0v[r] = __builtin_amdgcn_exp2f(s0v[r] - mnew);
      s1v[r] = __builtin_amdgcn_exp2f(s1v[r] - mnew);
      ps += s0v[r] + s1v[r];
    }
    ps += __shfl_xor(ps, 32);
    l_i = l_i * al + ps;
    #pragma unroll
    for (int d = 0; d < 4; ++d)
      #pragma unroll
      for (int r = 0; r < 16; ++r) acc[d][r] *= al;

    // ---- P^T: C-layout -> B-operand layout via cross-half shuffles ----
    // pk[m]: kv = 8*(m>>1) + 4*hi + 2*(m&1) + {0,1}
    u32 pk0[8], pk1[8], sh0[8], sh1[8];
    #pragma unroll
    for (int m = 0; m < 8; ++m) {
      pk0[m] = packbf(s0v[2 * m], s0v[2 * m + 1]);
      pk1[m] = packbf(s1v[2 * m], s1v[2 * m + 1]);
    }
    #pragma unroll
    for (int m = 0; m < 8; ++m) {
      sh0[m] = (u32)__shfl_xor((int)pk0[m], 32);
      sh1[m] = (u32)__shfl_xor((int)pk1[m], 32);
    }
    u32x4 bl0 = { hi ? sh0[2] : pk0[0], hi ? sh0[3] : pk0[1],
                  hi ? pk0[2] : sh0[0], hi ? pk0[3] : sh0[1] };
    u32x4 bh0 = { hi ? sh0[6] : pk0[4], hi ? sh0[7] : pk0[5],
                  hi ? pk0[6] : sh0[4], hi ? pk0[7] : sh0[5] };
    u32x4 bl1 = { hi ? sh1[2] : pk1[0], hi ? sh1[3] : pk1[1],
                  hi ? pk1[2] : sh1[0], hi ? pk1[3] : sh1[1] };
    u32x4 bh1 = { hi ? sh1[6] : pk1[4], hi ? sh1[7] : pk1[5],
                  hi ? pk1[6] : sh1[4], hi ? pk1[7] : sh1[5] };
    const bf16x8 pbl0 = __builtin_bit_cast(bf16x8, bl0);
    const bf16x8 pbh0 = __builtin_bit_cast(bf16x8, bh0);
    const bf16x8 pbl1 = __builtin_bit_cast(bf16x8, bl1);
    const bf16x8 pbh1 = __builtin_bit_cast(bf16x8, bh1);

    // ---- O^T += V^T P^T : A = Vs[d][kv] frags, B = P^T frags ----
    #pragma unroll
    for (int dt = 0; dt < 4; ++dt) {
      const u16* vrow = &Vs[dt * 32 + ln31][kh];
      acc[dt] = __builtin_amdgcn_mfma_f32_32x32x16_bf16(*(const bf16x8*)(vrow),      pbl0, acc[dt], 0, 0, 0);
      acc[dt] = __builtin_amdgcn_mfma_f32_32x32x16_bf16(*(const bf16x8*)(vrow + 16), pbh0, acc[dt], 0, 0, 0);
      acc[dt] = __builtin_amdgcn_mfma_f32_32x32x16_bf16(*(const bf16x8*)(vrow + 32), pbl1, acc[dt], 0, 0, 0);
      acc[dt] = __builtin_amdgcn_mfma_f32_32x32x16_bf16(*(const bf16x8*)(vrow + 48), pbh1, acc[dt], 0, 0, 0);
    }
  }

  // ---- epilogue: O^T C-layout -> row-major out, 16B stores, one rcp/lane ----
  const float inv = 1.0f / l_i;
  float* ob = Og + ((size_t)q * HQ + h) * DH;
  #pragma unroll
  for (int dt = 0; dt < 4; ++dt) {
    #pragma unroll
    for (int g = 0; g < 4; ++g) {     // d = dt*32 + 8*g + 4*hi + {0..3}
      float4 o = { acc[dt][4 * g + 0] * inv, acc[dt][4 * g + 1] * inv,
                   acc[dt][4 * g + 2] * inv, acc[dt][4 * g + 3] * inv };
      *(float4*)(ob + dt * 32 + 8 * g + 4 * hi) = o;
    }
  }
}

extern "C" void kernel_launch(void* const* d_in, const int* in_sizes, int n_in,
                              void* d_out, int out_size, void* d_ws, size_t ws_size,
                              hipStream_t stream) {
  const float* Qg = (const float*)d_in[0];
  const float* Kg = (const float*)d_in[1];
  const float* Vg = (const float*)d_in[2];
  float* Og = (float*)d_out;
  const int S = in_sizes[0] / (HQ * DH);   // 2176

  u16* Kr = (u16*)d_ws;                                     // 8*S*128 bf16 = 4.45 MB
  u16* Vt = (u16*)((char*)d_ws + (size_t)HKV * S * DH * 2); // 4.45 MB

  prep_kv<<<dim3(HKV, S / 64), dim3(256), 0, stream>>>(Kg, Vg, Kr, Vt, S);
  attn_main<<<dim3(HQ, S / 128), dim3(256), 0, stream>>>(Qg, Kr, Vt, Og, S);
}

// Round 4
// 136.264 us; speedup vs baseline: 1.5715x; 1.2994x over previous
//
#include <hip/hip_runtime.h>

#define HQ 32
#define HKV 8
#define DH 128
#define WIN 256
#define META 128
#define QSCALE 0.1275174324f    // rsqrt(128) * log2(e)  (scores produced in log2 space)
#define NFREQ 0.20762050594046f // log2(10000)/64: invfreq(i) = exp2(-NFREQ*i)

typedef __attribute__((ext_vector_type(8))) __bf16 bf16x8;
typedef __attribute__((ext_vector_type(16))) float f32x16;
typedef __attribute__((ext_vector_type(4))) unsigned int u32x4;
typedef unsigned short u16;
typedef unsigned int u32;

__device__ __forceinline__ u16 f2bf(float f) {
  u32 u = __float_as_uint(f);
  u += 0x7FFFu + ((u >> 16) & 1u);
  return (u16)(u >> 16);
}
__device__ __forceinline__ u32 packbf(float a, float b) {  // a->lo16, b->hi16
  u32 ua = __float_as_uint(a); ua += 0x7FFFu + ((ua >> 16) & 1u);
  u32 ub = __float_as_uint(b); ub += 0x7FFFu + ((ub >> 16) & 1u);
  return (ua >> 16) | (ub & 0xFFFF0000u);
}

// ---------- prep: RoPE(K) -> Kr[hk][s][d] bf16 ; V -> Vt[hk][d][s] bf16 ----------
__global__ __launch_bounds__(256)
void prep_kv(const float* __restrict__ Kg, const float* __restrict__ Vg,
             u16* __restrict__ Kr, u16* __restrict__ Vt, int S) {
  __shared__ float T[64][132];
  const int hk = blockIdx.x;
  const int s0 = blockIdx.y * 64;
  const int tid = threadIdx.x;
  // K rope: 4 threads/row, 16 pairs each
  {
    const int r = tid >> 2, c0 = (tid & 3) * 16;
    const int s = s0 + r;
    const float pos = (float)s;
    const float* src = Kg + ((size_t)s * HKV + hk) * DH;
    u16* dst = Kr + ((size_t)hk * S + s) * DH;
    float x[16], y[16];
    #pragma unroll
    for (int j = 0; j < 16; j += 4) {
      *(float4*)&x[j] = *(const float4*)(src + c0 + j);
      *(float4*)&y[j] = *(const float4*)(src + c0 + 64 + j);
    }
    u16 lo[16], hb[16];
    #pragma unroll
    for (int j = 0; j < 16; ++j) {
      float iv = __builtin_amdgcn_exp2f(-NFREQ * (float)(c0 + j));
      float sv, cv; __sincosf(pos * iv, &sv, &cv);
      lo[j] = f2bf(x[j] * cv - y[j] * sv);
      hb[j] = f2bf(y[j] * cv + x[j] * sv);
    }
    *(int4*)(dst + c0)      = *(int4*)&lo[0];
    *(int4*)(dst + c0 + 8)  = *(int4*)&lo[8];
    *(int4*)(dst + c0 + 64) = *(int4*)&hb[0];
    *(int4*)(dst + c0 + 72) = *(int4*)&hb[8];
  }
  // V transpose: stage fp32, write d-major bf16
  {
    const int r = tid >> 2, c = (tid & 3) * 32;
    const float* src = Vg + ((size_t)(s0 + r) * HKV + hk) * DH + c;
    #pragma unroll
    for (int j = 0; j < 32; j += 4) *(float4*)&T[r][c + j] = *(const float4*)(src + j);
  }
  __syncthreads();
  {
    const int d = tid >> 1, hf = (tid & 1) * 32;
    u16 buf[32];
    #pragma unroll
    for (int i = 0; i < 32; ++i) buf[i] = f2bf(T[hf + i][d]);
    u16* dst = Vt + ((size_t)hk * DH + d) * S + s0 + hf;
    #pragma unroll
    for (int j = 0; j < 4; ++j) *(int4*)(dst + j * 8) = *(int4*)&buf[j * 8];
  }
}

// ---------- main: flash attention, S^T/O^T orientation (q lives in lanes) ----------
// launch_bounds(256,2): 256 unified VGPR+AGPR per wave. (256,4) capped the budget
// at 128 -> acc[4] took 64 AGPR, rest spilled (~86 MB scratch writes, R3). Grid is
// 544 blocks ~= 2.1 blocks/CU so the extra occupancy bought nothing anyway.
__global__ __launch_bounds__(256, 2)
void attn_main(const float* __restrict__ Qg, const u16* __restrict__ Kr,
               const u16* __restrict__ Vt, float* __restrict__ Og, int S) {
  const int h = blockIdx.x;
  const int nqb = gridDim.y;
  const int q0 = (nqb - 1 - blockIdx.y) * 128;   // heavy blocks (more kv tiles) first
  const int hk = h >> 2;
  const int tid = threadIdx.x;
  const int lane = tid & 63;
  const int wave = tid >> 6;
  const int ln31 = lane & 31;
  const int hi = lane >> 5;
  const int kh = hi * 8;

  // Overlay: prologue Qs[128][136] (34816 B); loop Ks[64][136] + Vs[128][72] (35840 B)
  __shared__ __align__(16) char smem[35840];
  u16 (*Qs)[136] = (u16(*)[136])smem;
  u16 (*Ks)[136] = (u16(*)[136])smem;
  u16 (*Vs)[72]  = (u16(*)[72])(smem + 17408);

  // ---- prologue: stage Q with RoPE * QSCALE (log2e folded) ----
  {
    const int r = tid >> 1, c0 = (tid & 1) * 32;
    const float pos = (float)(q0 + r);
    const float* qrow = Qg + ((size_t)(q0 + r) * HQ + h) * DH;
    #pragma unroll
    for (int c = c0; c < c0 + 32; c += 8) {
      float x[8], y[8];
      *(float4*)&x[0] = *(const float4*)(qrow + c);
      *(float4*)&x[4] = *(const float4*)(qrow + c + 4);
      *(float4*)&y[0] = *(const float4*)(qrow + c + 64);
      *(float4*)&y[4] = *(const float4*)(qrow + c + 68);
      u16 lo[8], hb[8];
      #pragma unroll
      for (int j = 0; j < 8; ++j) {
        float iv = __builtin_amdgcn_exp2f(-NFREQ * (float)(c + j));
        float sv, cv; __sincosf(pos * iv, &sv, &cv);
        lo[j] = f2bf((x[j] * cv - y[j] * sv) * QSCALE);
        hb[j] = f2bf((y[j] * cv + x[j] * sv) * QSCALE);
      }
      __builtin_memcpy(&Qs[r][c], lo, 16);
      __builtin_memcpy(&Qs[r][c + 64], hb, 16);
    }
  }
  __syncthreads();
  const int qw0 = q0 + wave * 32;
  const int q = qw0 + ln31;           // this lane's q row (S^T col)
  bf16x8 qa[8];                       // B-operand frags: Q[q][k = kh + 16*kk + j]
  {
    const u16* qb = &Qs[wave * 32 + ln31][kh];
    #pragma unroll
    for (int kk = 0; kk < 8; ++kk) qa[kk] = *(const bf16x8*)(qb + kk * 16);
  }
  // loop-top __syncthreads() orders Qs reads before Ks/Vs overwrite

  int wstart = q0 - WIN; if (wstart < META) wstart = META;
  int nwin = (q0 + 128 - wstart) >> 6; if (nwin < 0) nwin = 0;
  const int ntiles = 2 + nwin;        // meta tiles first (guarantees finite m after t=0)

  f32x16 acc[4];                      // O^T: acc[dt] rows d=dt*32+pattern, col q=lane
  #pragma unroll
  for (int d = 0; d < 4; ++d)
    #pragma unroll
    for (int r = 0; r < 16; ++r) acc[d][r] = 0.f;
  float m_i = -1e30f, l_i = 0.f;      // one scalar per lane(=q row)

  const u16* Kb = Kr + (size_t)hk * S * DH;
  const u16* Vb = Vt + ((size_t)hk * DH + (tid >> 1)) * S + (tid & 1) * 32;
  const int kr = tid >> 2, kc = (tid & 3) * 32;

  for (int t = 0; t < ntiles; ++t) {
    const int kv0 = (t < 2) ? t * 64 : wstart + (t - 2) * 64;

    __syncthreads();  // previous tile's readers done (t=0: Qs frag reads done)
    {   // stage K tile: 64 rows x 128d, 64 B/thread
      const int4* ks = (const int4*)(Kb + (size_t)(kv0 + kr) * DH + kc);
      int4 a = ks[0], b = ks[1], c = ks[2], d = ks[3];
      int4* kd = (int4*)&Ks[kr][kc];
      kd[0] = a; kd[1] = b; kd[2] = c; kd[3] = d;
    }
    {   // stage V^T tile: 128 d-rows x 64 kv, 64 B/thread
      const int4* vs = (const int4*)(Vb + kv0);
      int4 a = vs[0], b = vs[1], c = vs[2], d = vs[3];
      int4* vd = (int4*)&Vs[tid >> 1][(tid & 1) * 32];
      vd[0] = a; vd[1] = b; vd[2] = c; vd[3] = d;
    }
    __syncthreads();

    // wave-active: causal reach AND not window-expired (meta tiles never expire)
    const bool active = (kv0 <= qw0 + 31) &&
                        ((kv0 < META) || (qw0 - kv0 - 63 <= WIN));
    if (!active) continue;

    // ---- S^T = K Q^T : two 32x32 C-tiles (kv rows in regs, q in lanes) ----
    f32x16 s0v, s1v;
    #pragma unroll
    for (int r = 0; r < 16; ++r) { s0v[r] = 0.f; s1v[r] = 0.f; }
    const u16* ka0 = &Ks[ln31][kh];
    const u16* ka1 = &Ks[32 + ln31][kh];
    #pragma unroll
    for (int kk = 0; kk < 8; ++kk)
      s0v = __builtin_amdgcn_mfma_f32_32x32x16_bf16(*(const bf16x8*)(ka0 + kk * 16), qa[kk], s0v, 0, 0, 0);
    #pragma unroll
    for (int kk = 0; kk < 8; ++kk)
      s1v = __builtin_amdgcn_mfma_f32_32x32x16_bf16(*(const bf16x8*)(ka1 + kk * 16), qa[kk], s1v, 0, 0, 0);

    // ---- mask (in-register, per kv value) ----
    const bool fullv = (kv0 + 63 <= qw0) &&
                       ((kv0 + 63 < META) || (qw0 + 31 - kv0 <= WIN));
    if (!fullv) {
      #pragma unroll
      for (int r = 0; r < 16; ++r) {
        const int kva = kv0 + (r & 3) + 8 * (r >> 2) + 4 * hi;
        const int kvb = kva + 32;
        if (!((kva <= q) && (((q - kva) <= WIN) || (kva < META)))) s0v[r] = -1e30f;
        if (!((kvb <= q) && (((q - kvb) <= WIN) || (kvb < META)))) s1v[r] = -1e30f;
      }
    }

    // ---- online softmax: register reduction + ONE cross-half shuffle each ----
    float mx = -1e30f;
    #pragma unroll
    for (int r = 0; r < 16; ++r) mx = fmaxf(mx, fmaxf(s0v[r], s1v[r]));
    mx = fmaxf(mx, __shfl_xor(mx, 32));
    const float mnew = fmaxf(m_i, mx);
    const float al = __builtin_amdgcn_exp2f(m_i - mnew);
    m_i = mnew;
    float ps = 0.f;
    #pragma unroll
    for (int r = 0; r < 16; ++r) {
      s0v[r] = __builtin_amdgcn_exp2f(s0v[r] - mnew);
      s1v[r] = __builtin_amdgcn_exp2f(s1v[r] - mnew);
      ps += s0v[r] + s1v[r];
    }
    ps += __shfl_xor(ps, 32);
    l_i = l_i * al + ps;
    #pragma unroll
    for (int d = 0; d < 4; ++d)
      #pragma unroll
      for (int r = 0; r < 16; ++r) acc[d][r] *= al;

    // ---- P^T: C-layout -> B-operand layout via cross-half shuffles ----
    // pk[m]: kv = 8*(m>>1) + 4*hi + 2*(m&1) + {0,1}
    u32 pk0[8], pk1[8], sh0[8], sh1[8];
    #pragma unroll
    for (int m = 0; m < 8; ++m) {
      pk0[m] = packbf(s0v[2 * m], s0v[2 * m + 1]);
      pk1[m] = packbf(s1v[2 * m], s1v[2 * m + 1]);
    }
    #pragma unroll
    for (int m = 0; m < 8; ++m) {
      sh0[m] = (u32)__shfl_xor((int)pk0[m], 32);
      sh1[m] = (u32)__shfl_xor((int)pk1[m], 32);
    }
    u32x4 bl0 = { hi ? sh0[2] : pk0[0], hi ? sh0[3] : pk0[1],
                  hi ? pk0[2] : sh0[0], hi ? pk0[3] : sh0[1] };
    u32x4 bh0 = { hi ? sh0[6] : pk0[4], hi ? sh0[7] : pk0[5],
                  hi ? pk0[6] : sh0[4], hi ? pk0[7] : sh0[5] };
    u32x4 bl1 = { hi ? sh1[2] : pk1[0], hi ? sh1[3] : pk1[1],
                  hi ? pk1[2] : sh1[0], hi ? pk1[3] : sh1[1] };
    u32x4 bh1 = { hi ? sh1[6] : pk1[4], hi ? sh1[7] : pk1[5],
                  hi ? pk1[6] : sh1[4], hi ? pk1[7] : sh1[5] };
    const bf16x8 pbl0 = __builtin_bit_cast(bf16x8, bl0);
    const bf16x8 pbh0 = __builtin_bit_cast(bf16x8, bh0);
    const bf16x8 pbl1 = __builtin_bit_cast(bf16x8, bl1);
    const bf16x8 pbh1 = __builtin_bit_cast(bf16x8, bh1);

    // ---- O^T += V^T P^T : A = Vs[d][kv] frags, B = P^T frags ----
    #pragma unroll
    for (int dt = 0; dt < 4; ++dt) {
      const u16* vrow = &Vs[dt * 32 + ln31][kh];
      acc[dt] = __builtin_amdgcn_mfma_f32_32x32x16_bf16(*(const bf16x8*)(vrow),      pbl0, acc[dt], 0, 0, 0);
      acc[dt] = __builtin_amdgcn_mfma_f32_32x32x16_bf16(*(const bf16x8*)(vrow + 16), pbh0, acc[dt], 0, 0, 0);
      acc[dt] = __builtin_amdgcn_mfma_f32_32x32x16_bf16(*(const bf16x8*)(vrow + 32), pbl1, acc[dt], 0, 0, 0);
      acc[dt] = __builtin_amdgcn_mfma_f32_32x32x16_bf16(*(const bf16x8*)(vrow + 48), pbh1, acc[dt], 0, 0, 0);
    }
  }

  // ---- epilogue: O^T C-layout -> row-major out, 16B stores, one rcp/lane ----
  const float inv = 1.0f / l_i;
  float* ob = Og + ((size_t)q * HQ + h) * DH;
  #pragma unroll
  for (int dt = 0; dt < 4; ++dt) {
    #pragma unroll
    for (int g = 0; g < 4; ++g) {     // d = dt*32 + 8*g + 4*hi + {0..3}
      float4 o = { acc[dt][4 * g + 0] * inv, acc[dt][4 * g + 1] * inv,
                   acc[dt][4 * g + 2] * inv, acc[dt][4 * g + 3] * inv };
      *(float4*)(ob + dt * 32 + 8 * g + 4 * hi) = o;
    }
  }
}

extern "C" void kernel_launch(void* const* d_in, const int* in_sizes, int n_in,
                              void* d_out, int out_size, void* d_ws, size_t ws_size,
                              hipStream_t stream) {
  const float* Qg = (const float*)d_in[0];
  const float* Kg = (const float*)d_in[1];
  const float* Vg = (const float*)d_in[2];
  float* Og = (float*)d_out;
  const int S = in_sizes[0] / (HQ * DH);   // 2176

  u16* Kr = (u16*)d_ws;                                     // 8*S*128 bf16 = 4.45 MB
  u16* Vt = (u16*)((char*)d_ws + (size_t)HKV * S * DH * 2); // 4.45 MB

  prep_kv<<<dim3(HKV, S / 64), dim3(256), 0, stream>>>(Kg, Vg, Kr, Vt, S);
  attn_main<<<dim3(HQ, S / 128), dim3(256), 0, stream>>>(Qg, Kr, Vt, Og, S);
}

// Round 5
// 133.275 us; speedup vs baseline: 1.6067x; 1.0224x over previous
//
#include <hip/hip_runtime.h>

#define HQ 32
#define HKV 8
#define DH 128
#define WIN 256
#define META 128
#define QSCALE 0.1275174324f    // rsqrt(128) * log2(e)  (scores produced in log2 space)
#define NFREQ 0.20762050594046f // log2(10000)/64: invfreq(i) = exp2(-NFREQ*i)

typedef __attribute__((ext_vector_type(8))) __bf16 bf16x8;
typedef __attribute__((ext_vector_type(16))) float f32x16;
typedef __attribute__((ext_vector_type(4))) unsigned int u32x4;
typedef unsigned short u16;
typedef unsigned int u32;

__device__ __forceinline__ u16 f2bf(float f) {
  u32 u = __float_as_uint(f);
  u += 0x7FFFu + ((u >> 16) & 1u);
  return (u16)(u >> 16);
}
__device__ __forceinline__ u32 packbf(float a, float b) {  // a->lo16, b->hi16
  u32 ua = __float_as_uint(a); ua += 0x7FFFu + ((ua >> 16) & 1u);
  u32 ub = __float_as_uint(b); ub += 0x7FFFu + ((ub >> 16) & 1u);
  return (ua >> 16) | (ub & 0xFFFF0000u);
}

// ---------- prep: RoPE(K) -> Kr[hk][s][d] bf16 ; V -> Vt[hk][d][s] bf16 ----------
__global__ __launch_bounds__(256)
void prep_kv(const float* __restrict__ Kg, const float* __restrict__ Vg,
             u16* __restrict__ Kr, u16* __restrict__ Vt, int S) {
  __shared__ float T[64][132];
  const int hk = blockIdx.x;
  const int s0 = blockIdx.y * 64;
  const int tid = threadIdx.x;
  // K rope: 4 threads/row, 16 pairs each
  {
    const int r = tid >> 2, c0 = (tid & 3) * 16;
    const int s = s0 + r;
    const float pos = (float)s;
    const float* src = Kg + ((size_t)s * HKV + hk) * DH;
    u16* dst = Kr + ((size_t)hk * S + s) * DH;
    float x[16], y[16];
    #pragma unroll
    for (int j = 0; j < 16; j += 4) {
      *(float4*)&x[j] = *(const float4*)(src + c0 + j);
      *(float4*)&y[j] = *(const float4*)(src + c0 + 64 + j);
    }
    u16 lo[16], hb[16];
    #pragma unroll
    for (int j = 0; j < 16; ++j) {
      float iv = __builtin_amdgcn_exp2f(-NFREQ * (float)(c0 + j));
      float sv, cv; __sincosf(pos * iv, &sv, &cv);
      lo[j] = f2bf(x[j] * cv - y[j] * sv);
      hb[j] = f2bf(y[j] * cv + x[j] * sv);
    }
    *(int4*)(dst + c0)      = *(int4*)&lo[0];
    *(int4*)(dst + c0 + 8)  = *(int4*)&lo[8];
    *(int4*)(dst + c0 + 64) = *(int4*)&hb[0];
    *(int4*)(dst + c0 + 72) = *(int4*)&hb[8];
  }
  // V transpose: stage fp32, write d-major bf16
  {
    const int r = tid >> 2, c = (tid & 3) * 32;
    const float* src = Vg + ((size_t)(s0 + r) * HKV + hk) * DH + c;
    #pragma unroll
    for (int j = 0; j < 32; j += 4) *(float4*)&T[r][c + j] = *(const float4*)(src + j);
  }
  __syncthreads();
  {
    const int d = tid >> 1, hf = (tid & 1) * 32;
    u16 buf[32];
    #pragma unroll
    for (int i = 0; i < 32; ++i) buf[i] = f2bf(T[hf + i][d]);
    u16* dst = Vt + ((size_t)hk * DH + d) * S + s0 + hf;
    #pragma unroll
    for (int j = 0; j < 4; ++j) *(int4*)(dst + j * 8) = *(int4*)&buf[j * 8];
  }
}

// Register prefetch of next KV tile. NAMED scalars, no arrays/lambdas:
// R2's lambda-captured arrays were alloca'd -> 106 MB scratch traffic.
#define LOAD_KV(kv0_) do {                                                 \
    const int4* ks_ = (const int4*)(Kb + (size_t)((kv0_) + kr) * DH + kc); \
    fk0 = ks_[0]; fk1 = ks_[1]; fk2 = ks_[2]; fk3 = ks_[3];                \
    const int4* vs_ = (const int4*)(Vb + (kv0_));                          \
    fv0 = vs_[0]; fv1 = vs_[1]; fv2 = vs_[2]; fv3 = vs_[3];                \
  } while (0)

#define STORE_KV() do {                                                    \
    int4* kd_ = (int4*)&Ks[kr][kc];                                        \
    kd_[0] = fk0; kd_[1] = fk1; kd_[2] = fk2; kd_[3] = fk3;                \
    int4* vd_ = (int4*)&Vs[tid >> 1][(tid & 1) * 32];                      \
    vd_[0] = fv0; vd_[1] = fv1; vd_[2] = fv2; vd_[3] = fv3;                \
  } while (0)

// ---------- main: flash attention, S^T/O^T orientation (q lives in lanes) ----------
// launch_bounds(256,2): 256 unified VGPR+AGPR per wave; (256,4) caps at 128 -> spills.
// Grid 544 blocks ~= 2.1 blocks/CU, so extra occupancy is unreachable anyway.
__global__ __launch_bounds__(256, 2)
void attn_main(const float* __restrict__ Qg, const u16* __restrict__ Kr,
               const u16* __restrict__ Vt, float* __restrict__ Og, int S) {
  const int h = blockIdx.x;
  const int nqb = gridDim.y;
  const int q0 = (nqb - 1 - blockIdx.y) * 128;   // heavy blocks (more kv tiles) first
  const int hk = h >> 2;
  const int tid = threadIdx.x;
  const int lane = tid & 63;
  const int wave = tid >> 6;
  const int ln31 = lane & 31;
  const int hi = lane >> 5;
  const int kh = hi * 8;

  // Overlay: prologue Qs[128][136] (34816 B); loop Ks[64][136] + Vs[128][72] (35840 B)
  __shared__ __align__(16) char smem[35840];
  u16 (*Qs)[136] = (u16(*)[136])smem;
  u16 (*Ks)[136] = (u16(*)[136])smem;
  u16 (*Vs)[72]  = (u16(*)[72])(smem + 17408);

  const u16* Kb = Kr + (size_t)hk * S * DH;
  const u16* Vb = Vt + ((size_t)hk * DH + (tid >> 1)) * S + (tid & 1) * 32;
  const int kr = tid >> 2, kc = (tid & 3) * 32;

  int4 fk0, fk1, fk2, fk3, fv0, fv1, fv2, fv3;
  LOAD_KV(0);   // tile-0 loads fly while we do the whole Q prologue

  // ---- prologue: stage Q with RoPE * QSCALE (log2e folded) ----
  {
    const int r = tid >> 1, c0 = (tid & 1) * 32;
    const float pos = (float)(q0 + r);
    const float* qrow = Qg + ((size_t)(q0 + r) * HQ + h) * DH;
    #pragma unroll
    for (int c = c0; c < c0 + 32; c += 8) {
      float x[8], y[8];
      *(float4*)&x[0] = *(const float4*)(qrow + c);
      *(float4*)&x[4] = *(const float4*)(qrow + c + 4);
      *(float4*)&y[0] = *(const float4*)(qrow + c + 64);
      *(float4*)&y[4] = *(const float4*)(qrow + c + 68);
      u16 lo[8], hb[8];
      #pragma unroll
      for (int j = 0; j < 8; ++j) {
        float iv = __builtin_amdgcn_exp2f(-NFREQ * (float)(c + j));
        float sv, cv; __sincosf(pos * iv, &sv, &cv);
        lo[j] = f2bf((x[j] * cv - y[j] * sv) * QSCALE);
        hb[j] = f2bf((y[j] * cv + x[j] * sv) * QSCALE);
      }
      __builtin_memcpy(&Qs[r][c], lo, 16);
      __builtin_memcpy(&Qs[r][c + 64], hb, 16);
    }
  }
  __syncthreads();
  const int qw0 = q0 + wave * 32;
  const int q = qw0 + ln31;           // this lane's q row (S^T col)
  bf16x8 qa[8];                       // B-operand frags: Q[q][k = kh + 16*kk + j]
  {
    const u16* qb = &Qs[wave * 32 + ln31][kh];
    #pragma unroll
    for (int kk = 0; kk < 8; ++kk) qa[kk] = *(const bf16x8*)(qb + kk * 16);
  }
  __syncthreads();   // Qs reads done; region becomes Ks/Vs
  STORE_KV();        // tile 0 into LDS (vmcnt wait covered by prologue)
  __syncthreads();

  int wstart = q0 - WIN; if (wstart < META) wstart = META;
  int nwin = (q0 + 128 - wstart) >> 6; if (nwin < 0) nwin = 0;
  const int ntiles = 2 + nwin;        // meta tiles first (guarantees finite m after t=0)

  f32x16 acc[4];                      // O^T: acc[dt] rows d=dt*32+pattern, col q=lane
  #pragma unroll
  for (int d = 0; d < 4; ++d)
    #pragma unroll
    for (int r = 0; r < 16; ++r) acc[d][r] = 0.f;
  float m_i = -1e30f, l_i = 0.f;      // one scalar per lane(=q row)

  for (int t = 0; t < ntiles; ++t) {
    const int kv0 = (t < 2) ? t * 64 : wstart + (t - 2) * 64;
    const bool haveNext = (t + 1 < ntiles);
    if (haveNext) {                   // issue next tile's loads; ~full tile to land
      const int kvn = (t + 1 < 2) ? (t + 1) * 64 : wstart + (t - 1) * 64;
      LOAD_KV(kvn);
    }

    // wave-active: causal reach AND not window-expired (meta tiles never expire)
    const bool active = (kv0 <= qw0 + 31) &&
                        ((kv0 < META) || (qw0 - kv0 - 63 <= WIN));
    if (active) {
      // ---- S^T = K Q^T : two 32x32 C-tiles (kv rows in regs, q in lanes) ----
      f32x16 s0v, s1v;
      #pragma unroll
      for (int r = 0; r < 16; ++r) { s0v[r] = 0.f; s1v[r] = 0.f; }
      const u16* ka0 = &Ks[ln31][kh];
      const u16* ka1 = &Ks[32 + ln31][kh];
      #pragma unroll
      for (int kk = 0; kk < 8; ++kk)
        s0v = __builtin_amdgcn_mfma_f32_32x32x16_bf16(*(const bf16x8*)(ka0 + kk * 16), qa[kk], s0v, 0, 0, 0);
      #pragma unroll
      for (int kk = 0; kk < 8; ++kk)
        s1v = __builtin_amdgcn_mfma_f32_32x32x16_bf16(*(const bf16x8*)(ka1 + kk * 16), qa[kk], s1v, 0, 0, 0);

      // ---- mask (in-register, per kv value) ----
      const bool fullv = (kv0 + 63 <= qw0) &&
                         ((kv0 + 63 < META) || (qw0 + 31 - kv0 <= WIN));
      if (!fullv) {
        #pragma unroll
        for (int r = 0; r < 16; ++r) {
          const int kva = kv0 + (r & 3) + 8 * (r >> 2) + 4 * hi;
          const int kvb = kva + 32;
          if (!((kva <= q) && (((q - kva) <= WIN) || (kva < META)))) s0v[r] = -1e30f;
          if (!((kvb <= q) && (((q - kvb) <= WIN) || (kvb < META)))) s1v[r] = -1e30f;
        }
      }

      // ---- online softmax: register reduction + ONE cross-half shuffle each ----
      float mx = -1e30f;
      #pragma unroll
      for (int r = 0; r < 16; ++r) mx = fmaxf(mx, fmaxf(s0v[r], s1v[r]));
      mx = fmaxf(mx, __shfl_xor(mx, 32));
      const float mnew = fmaxf(m_i, mx);
      const float al = __builtin_amdgcn_exp2f(m_i - mnew);
      m_i = mnew;
      float ps = 0.f;
      #pragma unroll
      for (int r = 0; r < 16; ++r) {
        s0v[r] = __builtin_amdgcn_exp2f(s0v[r] - mnew);
        s1v[r] = __builtin_amdgcn_exp2f(s1v[r] - mnew);
        ps += s0v[r] + s1v[r];
      }
      ps += __shfl_xor(ps, 32);
      l_i = l_i * al + ps;
      #pragma unroll
      for (int d = 0; d < 4; ++d)
        #pragma unroll
        for (int r = 0; r < 16; ++r) acc[d][r] *= al;

      // ---- P^T: C-layout -> B-operand layout via cross-half shuffles ----
      // pk[m]: kv = 8*(m>>1) + 4*hi + 2*(m&1) + {0,1}
      u32 pk0[8], pk1[8], sh0[8], sh1[8];
      #pragma unroll
      for (int m = 0; m < 8; ++m) {
        pk0[m] = packbf(s0v[2 * m], s0v[2 * m + 1]);
        pk1[m] = packbf(s1v[2 * m], s1v[2 * m + 1]);
      }
      #pragma unroll
      for (int m = 0; m < 8; ++m) {
        sh0[m] = (u32)__shfl_xor((int)pk0[m], 32);
        sh1[m] = (u32)__shfl_xor((int)pk1[m], 32);
      }
      u32x4 bl0 = { hi ? sh0[2] : pk0[0], hi ? sh0[3] : pk0[1],
                    hi ? pk0[2] : sh0[0], hi ? pk0[3] : sh0[1] };
      u32x4 bh0 = { hi ? sh0[6] : pk0[4], hi ? sh0[7] : pk0[5],
                    hi ? pk0[6] : sh0[4], hi ? pk0[7] : sh0[5] };
      u32x4 bl1 = { hi ? sh1[2] : pk1[0], hi ? sh1[3] : pk1[1],
                    hi ? pk1[2] : sh1[0], hi ? pk1[3] : sh1[1] };
      u32x4 bh1 = { hi ? sh1[6] : pk1[4], hi ? sh1[7] : pk1[5],
                    hi ? pk1[6] : sh1[4], hi ? pk1[7] : sh1[5] };
      const bf16x8 pbl0 = __builtin_bit_cast(bf16x8, bl0);
      const bf16x8 pbh0 = __builtin_bit_cast(bf16x8, bh0);
      const bf16x8 pbl1 = __builtin_bit_cast(bf16x8, bl1);
      const bf16x8 pbh1 = __builtin_bit_cast(bf16x8, bh1);

      // ---- O^T += V^T P^T : A = Vs[d][kv] frags, B = P^T frags ----
      #pragma unroll
      for (int dt = 0; dt < 4; ++dt) {
        const u16* vrow = &Vs[dt * 32 + ln31][kh];
        acc[dt] = __builtin_amdgcn_mfma_f32_32x32x16_bf16(*(const bf16x8*)(vrow),      pbl0, acc[dt], 0, 0, 0);
        acc[dt] = __builtin_amdgcn_mfma_f32_32x32x16_bf16(*(const bf16x8*)(vrow + 16), pbh0, acc[dt], 0, 0, 0);
        acc[dt] = __builtin_amdgcn_mfma_f32_32x32x16_bf16(*(const bf16x8*)(vrow + 32), pbl1, acc[dt], 0, 0, 0);
        acc[dt] = __builtin_amdgcn_mfma_f32_32x32x16_bf16(*(const bf16x8*)(vrow + 48), pbh1, acc[dt], 0, 0, 0);
      }
    }

    if (haveNext) {
      __syncthreads();   // all waves done reading Ks/Vs
      STORE_KV();        // prefetched tile -> LDS (loads landed during compute)
      __syncthreads();
    }
  }

  // ---- epilogue: O^T C-layout -> row-major out, 16B stores, one rcp/lane ----
  const float inv = 1.0f / l_i;
  float* ob = Og + ((size_t)q * HQ + h) * DH;
  #pragma unroll
  for (int dt = 0; dt < 4; ++dt) {
    #pragma unroll
    for (int g = 0; g < 4; ++g) {     // d = dt*32 + 8*g + 4*hi + {0..3}
      float4 o = { acc[dt][4 * g + 0] * inv, acc[dt][4 * g + 1] * inv,
                   acc[dt][4 * g + 2] * inv, acc[dt][4 * g + 3] * inv };
      *(float4*)(ob + dt * 32 + 8 * g + 4 * hi) = o;
    }
  }
}

extern "C" void kernel_launch(void* const* d_in, const int* in_sizes, int n_in,
                              void* d_out, int out_size, void* d_ws, size_t ws_size,
                              hipStream_t stream) {
  const float* Qg = (const float*)d_in[0];
  const float* Kg = (const float*)d_in[1];
  const float* Vg = (const float*)d_in[2];
  float* Og = (float*)d_out;
  const int S = in_sizes[0] / (HQ * DH);   // 2176

  u16* Kr = (u16*)d_ws;                                     // 8*S*128 bf16 = 4.45 MB
  u16* Vt = (u16*)((char*)d_ws + (size_t)HKV * S * DH * 2); // 4.45 MB

  prep_kv<<<dim3(HKV, S / 64), dim3(256), 0, stream>>>(Kg, Vg, Kr, Vt, S);
  attn_main<<<dim3(HQ, S / 128), dim3(256), 0, stream>>>(Qg, Kr, Vt, Og, S);
}